// Round 1
// 188.631 us; speedup vs baseline: 1.1318x; 1.1318x over previous
//
#include <hip/hip_runtime.h>
#include <hip/hip_bf16.h>

#define B_ 8
#define L_ 2048
#define DM 512
#define E_ 64
#define H_ 64
#define R_ 4
#define KC 3
#define BL (B_*L_)   // 16384
#define NX 132       // R + 2H
#define LC 128       // scan chunk length
#define NCH (L_/LC)  // 16 chunks

typedef __attribute__((ext_vector_type(8))) short bfrag;
typedef __attribute__((ext_vector_type(4))) float facc;
typedef unsigned int u32;

#define LOG2E 1.4426950408889634f

__device__ __forceinline__ unsigned short f2b(float f) {
  __hip_bfloat16 h = __float2bfloat16(f);
  return *reinterpret_cast<unsigned short*>(&h);
}
__device__ __forceinline__ float b2f16(unsigned short u) {
  return __uint_as_float((unsigned)u << 16);
}
__device__ __forceinline__ bfrag ld_frag(const unsigned short* p) {
  bfrag t;
  __builtin_memcpy(&t, p, 16);
  return t;
}

// ---- K0: fold W_dt into W_x -> WFT bf16 [192][64] (n-major). 192 blocks x 64 thr.
__global__ __launch_bounds__(64) void k_wfuse(
    const float* __restrict__ Wx, const float* __restrict__ Wdt,
    unsigned short* __restrict__ WFT)
{
  const int n = blockIdx.x;
  const int e = threadIdx.x;
  float v;
  if (n < 64) {
    v = 0.f;
    #pragma unroll
    for (int j = 0; j < R_; ++j)
      v = fmaf(Wx[e * NX + j], Wdt[j * 64 + n], v);
  } else if (n < 128) {
    v = Wx[e * NX + R_ + (n - 64)];
  } else {
    v = Wx[e * NX + R_ + 64 + (n - 128)];
  }
  WFT[n * 64 + e] = f2b(v);
}

// ---- K1 (MFMA, dbuf LDS — SAFE: staging always writes the other buffer):
// xz = x @ W_in ; cols 0..63 -> xp_pre[token][64], 64..127 -> resT
__global__ __launch_bounds__(256) void k_gemm_in(
    const float* __restrict__ x, const float* __restrict__ Win,
    float* __restrict__ xp_pre, float* __restrict__ resT)
{
  __shared__ unsigned short As[2][32][36];
  __shared__ unsigned short Bs[2][128][36];
  const int tid  = threadIdx.x;
  const int m0   = blockIdx.x * 32;
  const int b    = m0 >> 11;
  const int l0   = m0 & 2047;
  const int lane = tid & 63;
  const int wave = tid >> 6;
  const int mt   = wave & 1;
  const int ng   = wave >> 1;
  const int nl   = lane & 15;
  const int g    = lane >> 4;
  facc acc[4];
  #pragma unroll
  for (int j = 0; j < 4; ++j) acc[j] = (facc)(0.f);

  auto stage = [&](int sel, int k0) {
    {
      int r = tid >> 3, q = tid & 7;
      float4 v = *(const float4*)&x[(size_t)(m0 + r) * DM + k0 + 4 * q];
      ushort4 u;
      u.x = f2b(v.x); u.y = f2b(v.y); u.z = f2b(v.z); u.w = f2b(v.w);
      *(ushort4*)&As[sel][r][4 * q] = u;
    }
    #pragma unroll
    for (int p = 0; p < 4; ++p) {
      int fidx = tid + 256 * p;
      int r = fidx >> 5, cq = fidx & 31;
      float4 v = *(const float4*)&Win[(size_t)(k0 + r) * 128 + 4 * cq];
      Bs[sel][4 * cq + 0][r] = f2b(v.x);
      Bs[sel][4 * cq + 1][r] = f2b(v.y);
      Bs[sel][4 * cq + 2][r] = f2b(v.z);
      Bs[sel][4 * cq + 3][r] = f2b(v.w);
    }
  };

  stage(0, 0);
  __syncthreads();
  for (int it = 0; it < 16; ++it) {
    const int cur = it & 1;
    if (it + 1 < 16) stage(cur ^ 1, (it + 1) * 32);
    bfrag af = ld_frag(&As[cur][mt * 16 + nl][g * 8]);
    #pragma unroll
    for (int nt2 = 0; nt2 < 4; ++nt2) {
      bfrag bfr = ld_frag(&Bs[cur][(ng * 4 + nt2) * 16 + nl][g * 8]);
      acc[nt2] = __builtin_amdgcn_mfma_f32_16x16x32_bf16(af, bfr, acc[nt2], 0, 0, 0);
    }
    __syncthreads();
  }
  #pragma unroll
  for (int nt2 = 0; nt2 < 4; ++nt2) {
    facc a = acc[nt2];
    int c = (ng * 4 + nt2) * 16 + nl;
    int mrow = mt * 16 + 4 * g;
    if (c < 64) {
      #pragma unroll
      for (int r = 0; r < 4; ++r)
        xp_pre[(size_t)(m0 + mrow + r) * 64 + c] = a[r];
    } else {
      *(float4*)&resT[(size_t)(b * 64 + (c - 64)) * L_ + l0 + mrow] =
          make_float4(a[0], a[1], a[2], a[3]);
    }
  }
}

// ---- K2 (fused, MFMA — single-shot staging, 2 barriers, no re-staging):
// conv+silu -> xpT + bf16 A-tile ; [delta|B|C] = xp @ WF ; softplus -> deltaT ;
// B and C packed into one u32 per (token,h): low = B bf16 bits, high = C bf16 bits.
__global__ __launch_bounds__(256) void k_fused(
    const float* __restrict__ xp_pre,
    const float* __restrict__ conv_w, const float* __restrict__ conv_b,
    const unsigned short* __restrict__ WFT, const float* __restrict__ bdt,
    float* __restrict__ xpT, float* __restrict__ deltaT,
    u32* __restrict__ BCm)
{
  __shared__ float raw[66][65];
  __shared__ unsigned short rawb[64][72];     // 144B rows, 16B aligned
  __shared__ unsigned short WFb[192][72];     // FULL K=64 rows: no aliasing, staged ONCE
  const int tid = threadIdx.x;
  const int t0 = blockIdx.x * 64;
  const int b  = t0 >> 11;
  const int l0 = t0 & 2047;
  // stage raw (zero-pad l<0)
  for (int fidx = tid; fidx < 66 * 16; fidx += 256) {
    int r = fidx >> 4, cg = fidx & 15;
    int l = l0 - 2 + r;
    float4 v = make_float4(0.f, 0.f, 0.f, 0.f);
    if (l >= 0) v = *(const float4*)&xp_pre[((size_t)b * L_ + l) * 64 + cg * 4];
    raw[r][cg * 4 + 0] = v.x;
    raw[r][cg * 4 + 1] = v.y;
    raw[r][cg * 4 + 2] = v.z;
    raw[r][cg * 4 + 3] = v.w;
  }
  // stage full WFb (192 rows x 64 k), ushort4 chunks; offsets 4*jq <= 60 < 72
  for (int i4 = tid; i4 < 192 * 16; i4 += 256) {
    int n = i4 >> 4, jq = i4 & 15;
    *(ushort4*)&WFb[n][jq * 4] = *(const ushort4*)&WFT[n * 64 + jq * 4];
  }
  __syncthreads();
  // conv + silu: thread -> (e, 16 tokens); write bf16 A-tile + xpT
  const int e  = tid & 63;
  const int tl = tid >> 6;
  const float w0 = conv_w[e * KC + 0], w1 = conv_w[e * KC + 1], w2 = conv_w[e * KC + 2];
  const float cb = conv_b[e];
  float cres[16];
  #pragma unroll
  for (int i = 0; i < 16; ++i) {
    int tok = tl * 16 + i;
    float a = cb;
    a = fmaf(raw[tok + 0][e], w0, a);
    a = fmaf(raw[tok + 1][e], w1, a);
    a = fmaf(raw[tok + 2][e], w2, a);
    cres[i] = a / (1.f + __expf(-a));
  }
  #pragma unroll
  for (int i = 0; i < 16; ++i) rawb[tl * 16 + i][e] = f2b(cres[i]);
  #pragma unroll
  for (int i = 0; i < 16; i += 4)
    *(float4*)&xpT[(size_t)(b * 64 + e) * L_ + l0 + tl * 16 + i] =
        make_float4(cres[i], cres[i + 1], cres[i + 2], cres[i + 3]);
  __syncthreads();
  // MFMA GEMM: M=64 (4 waves), N=192 (12 tiles), K=64 (2 ksteps) — all LDS read-only now
  const int wave = tid >> 6;
  const int lane = tid & 63;
  const int nl   = lane & 15;
  const int g    = lane >> 4;
  facc acc[12];
  #pragma unroll
  for (int j = 0; j < 12; ++j) acc[j] = (facc)(0.f);
  #pragma unroll
  for (int ks = 0; ks < 2; ++ks) {
    bfrag af = ld_frag(&rawb[wave * 16 + nl][ks * 32 + g * 8]);
    #pragma unroll
    for (int nt = 0; nt < 12; ++nt) {
      bfrag bfr = ld_frag(&WFb[nt * 16 + nl][ks * 32 + g * 8]);
      acc[nt] = __builtin_amdgcn_mfma_f32_16x16x32_bf16(af, bfr, acc[nt], 0, 0, 0);
    }
  }
  const int mrow = wave * 16 + 4 * g;
  // delta cols (0..63): softplus -> deltaT (transposed, coalesced)
  #pragma unroll
  for (int nt = 0; nt < 4; ++nt) {
    facc a = acc[nt];
    int c = nt * 16 + nl;
    float bias = bdt[c];
    float d0 = a[0] + bias, d1 = a[1] + bias, d2 = a[2] + bias, d3 = a[3] + bias;
    float4 dv;
    dv.x = (d0 > 20.f) ? d0 : log1pf(__expf(d0));
    dv.y = (d1 > 20.f) ? d1 : log1pf(__expf(d1));
    dv.z = (d2 > 20.f) ? d2 : log1pf(__expf(d2));
    dv.w = (d3 > 20.f) ? d3 : log1pf(__expf(d3));
    *(float4*)&deltaT[(size_t)(b * 64 + c) * L_ + l0 + mrow] = dv;
  }
  // B (nt 4..7) pairs with C (nt+4 = 8..11) at the same (row, col) -> pack u32
  #pragma unroll
  for (int nt = 4; nt < 8; ++nt) {
    facc aB = acc[nt];
    facc aC = acc[nt + 4];
    int col = (nt - 4) * 16 + nl;
    #pragma unroll
    for (int r = 0; r < 4; ++r)
      BCm[(size_t)(t0 + mrow + r) * 64 + col] =
          (u32)f2b(aB[r]) | ((u32)f2b(aC[r]) << 16);
  }
}

// ---- K3a: per-chunk summaries. 4 waves/block, wave-private LDS, no barriers.
// Whole chunk (128 tokens) staged once; w = d*x precomputed; exp folded to exp2.
__global__ __launch_bounds__(256) void k_scan1(
    const float* __restrict__ deltaT, const float* __restrict__ xpT,
    const u32* __restrict__ BCm, const float* __restrict__ A_log,
    float* __restrict__ Ssum, float* __restrict__ Pp)
{
  __shared__ float dwA[4][256];   // per wave: d[0..127], w[128..255]
  const int tid = threadIdx.x;
  const int wv  = tid >> 6;
  const int h   = tid & 63;
  const int id  = blockIdx.x * 4 + wv;
  const int c   = id & (NCH - 1);
  if (c == NCH - 1) return;       // last chunk's summary is never consumed
  const int e = (id >> 4) & 63;
  const int b = id >> 10;
  const float A2 = -__expf(A_log[e * 64 + h]) * LOG2E;   // A * log2(e)
  const size_t beL = (size_t)(b * 64 + e) * L_;
  const int l0 = c * LC;
  float* dw = dwA[wv];
  {
    float2 dv = *(const float2*)&deltaT[beL + l0 + 2 * h];
    float2 xv = *(const float2*)&xpT[beL + l0 + 2 * h];
    *(float2*)&dw[2 * h] = dv;
    *(float2*)&dw[128 + 2 * h] = make_float2(dv.x * xv.x, dv.y * xv.y);
  }
  const u32* bc = &BCm[(size_t)(b * L_ + l0) * 64 + h];
  float s = 0.f, sd = 0.f;
  #pragma unroll 2
  for (int k16 = 0; k16 < 8; ++k16) {
    #pragma unroll
    for (int kk = 0; kk < 16; ++kk) {
      const int k = k16 * 16 + kk;
      float dlt = dw[k];
      float w   = dw[128 + k];
      u32 u = bc[(size_t)k * 64];
      float Bh = __uint_as_float(u << 16);
      s = fmaf(__builtin_amdgcn_exp2f(dlt * A2), s, w * Bh);
      sd += dlt;
    }
  }
  const size_t idx = (size_t)id * 64 + h;
  Ssum[idx] = s;
  Pp[idx]   = __builtin_amdgcn_exp2f(A2 * sd);
}

// ---- K3c: scan per chunk. 4 waves/block, wave-private LDS, no barriers.
// Entry state composed inline; f32 tile reduce (no bf16 roundtrip); packed BC loads.
__global__ __launch_bounds__(256) void k_scan3(
    const float* __restrict__ deltaT, const float* __restrict__ xpT,
    const float* __restrict__ resT, const u32* __restrict__ BCm,
    const float* __restrict__ A_log, const float* __restrict__ Dp,
    const float* __restrict__ Ssum, const float* __restrict__ Pp,
    float* __restrict__ ygT)
{
  __shared__ float tileA[4][16][68];
  __shared__ float bufA[4][512];  // d[0..127] w[128..255] x[256..383] res[384..511]
  const int tid = threadIdx.x;
  const int wv  = tid >> 6;
  const int h   = tid & 63;
  const int id  = blockIdx.x * 4 + wv;
  const int c   = id & (NCH - 1);
  const int e   = (id >> 4) & 63;
  const int b   = id >> 10;
  const float A2 = -__expf(A_log[e * 64 + h]) * LOG2E;
  const float Dv = Dp[e];
  const size_t beL = (size_t)(b * 64 + e) * L_;
  float (*tile)[68] = tileA[wv];
  float* buf = bufA[wv];
  // compose entry state from chunk summaries 0..c-1 (global reads only)
  float s = 0.f;
  const size_t sbase = (size_t)(id & ~(NCH - 1)) * 64 + h;
  for (int cc = 0; cc < c; ++cc)
    s = fmaf(Pp[sbase + (size_t)cc * 64], s, Ssum[sbase + (size_t)cc * 64]);
  const int l0 = c * LC;
  {
    float2 dv = *(const float2*)&deltaT[beL + l0 + 2 * h];
    float2 xv = *(const float2*)&xpT[beL + l0 + 2 * h];
    float2 rv = *(const float2*)&resT[beL + l0 + 2 * h];
    *(float2*)&buf[2 * h]       = dv;
    *(float2*)&buf[128 + 2 * h] = make_float2(dv.x * xv.x, dv.y * xv.y);
    *(float2*)&buf[256 + 2 * h] = xv;
    *(float2*)&buf[384 + 2 * h] = rv;
  }
  const u32* bc = &BCm[(size_t)(b * L_ + l0) * 64 + h];
  const int r = h & 15, q = h >> 4;
  #pragma unroll 2
  for (int k16 = 0; k16 < 8; ++k16) {
    #pragma unroll
    for (int kk = 0; kk < 16; ++kk) {
      const int k = k16 * 16 + kk;
      float dlt = buf[k];
      float w   = buf[128 + k];
      u32 u = bc[(size_t)k * 64];
      s = fmaf(__builtin_amdgcn_exp2f(dlt * A2), s, w * __uint_as_float(u << 16));
      tile[kk][h] = s * __uint_as_float(u & 0xffff0000u);
    }
    // lane h: row r = h&15, quarter q = h>>4; sum 16 f32 then combine quarters
    float part = 0.f;
    const float4* rp = (const float4*)&tile[r][q * 16];
    #pragma unroll
    for (int jq = 0; jq < 4; ++jq) {
      float4 v = rp[jq];
      part += (v.x + v.y) + (v.z + v.w);
    }
    part += __shfl_xor(part, 16, 64);
    part += __shfl_xor(part, 32, 64);
    if (q == 0) {
      const int lk = k16 * 16 + r;
      float y = fmaf(buf[256 + lk], Dv, part);
      y *= __builtin_amdgcn_rcpf(1.f + __builtin_amdgcn_exp2f(-LOG2E * buf[384 + lk]));
      ygT[beL + l0 + lk] = y;
    }
  }
}

// ---- K4 (MFMA): out = ygT^T @ W_out. Single-shot staging + 1 barrier. 1024 blocks x 128 thr.
__global__ __launch_bounds__(128) void k_gemm_out(
    const float* __restrict__ ygT, const float* __restrict__ Wout,
    float* __restrict__ out)
{
  __shared__ unsigned short As[64][68];
  __shared__ unsigned short Bs[128][68];
  const int tid  = threadIdx.x;
  const int m0   = (blockIdx.x & 255) * 64;
  const int n0   = (blockIdx.x >> 8) * 128;
  const int b    = m0 >> 11;
  const int l0   = m0 & 2047;
  const int lane = tid & 63;
  const int wave = tid >> 6;
  const int nl   = lane & 15;
  const int g    = lane >> 4;
  #pragma unroll
  for (int p = 0; p < 8; ++p) {
    int fidx = tid + 128 * p;              // 0..1023
    int e = fidx >> 4, q = fidx & 15;
    float4 v = *(const float4*)&ygT[(size_t)(b * 64 + e) * L_ + l0 + 4 * q];
    As[4 * q + 0][e] = f2b(v.x);
    As[4 * q + 1][e] = f2b(v.y);
    As[4 * q + 2][e] = f2b(v.z);
    As[4 * q + 3][e] = f2b(v.w);
  }
  #pragma unroll
  for (int p = 0; p < 16; ++p) {
    int fidx = tid + 128 * p;
    int r = fidx >> 5, cq = fidx & 31;
    float4 v = *(const float4*)&Wout[(size_t)r * DM + n0 + 4 * cq];
    Bs[4 * cq + 0][r] = f2b(v.x);
    Bs[4 * cq + 1][r] = f2b(v.y);
    Bs[4 * cq + 2][r] = f2b(v.z);
    Bs[4 * cq + 3][r] = f2b(v.w);
  }
  __syncthreads();
  facc acc[2][8];
  #pragma unroll
  for (int i = 0; i < 2; ++i)
    #pragma unroll
    for (int j = 0; j < 8; ++j)
      acc[i][j] = (facc)(0.f);
  #pragma unroll
  for (int ks = 0; ks < 2; ++ks) {
    bfrag af0 = ld_frag(&As[wave * 32 + nl][ks * 32 + g * 8]);
    bfrag af1 = ld_frag(&As[wave * 32 + 16 + nl][ks * 32 + g * 8]);
    #pragma unroll
    for (int nt = 0; nt < 8; ++nt) {
      bfrag bfr = ld_frag(&Bs[nt * 16 + nl][ks * 32 + g * 8]);
      acc[0][nt] = __builtin_amdgcn_mfma_f32_16x16x32_bf16(af0, bfr, acc[0][nt], 0, 0, 0);
      acc[1][nt] = __builtin_amdgcn_mfma_f32_16x16x32_bf16(af1, bfr, acc[1][nt], 0, 0, 0);
    }
  }
  #pragma unroll
  for (int mt = 0; mt < 2; ++mt) {
    int mrow = m0 + wave * 32 + mt * 16 + 4 * g;
    #pragma unroll
    for (int nt = 0; nt < 8; ++nt) {
      facc a = acc[mt][nt];
      int c = n0 + nt * 16 + nl;
      #pragma unroll
      for (int r = 0; r < 4; ++r)
        out[(size_t)(mrow + r) * DM + c] = a[r];
    }
  }
}

extern "C" void kernel_launch(void* const* d_in, const int* in_sizes, int n_in,
                              void* d_out, int out_size, void* d_ws, size_t ws_size,
                              hipStream_t stream) {
  const float* x      = (const float*)d_in[0];
  const float* Win    = (const float*)d_in[1];
  const float* conv_w = (const float*)d_in[2];
  const float* conv_b = (const float*)d_in[3];
  const float* Wx     = (const float*)d_in[4];
  const float* Wdt    = (const float*)d_in[5];
  const float* bdt    = (const float*)d_in[6];
  const float* A_log  = (const float*)d_in[7];
  const float* Dp     = (const float*)d_in[8];
  const float* Wout   = (const float*)d_in[9];
  float* out = (float*)d_out;

  float* ws = (float*)d_ws;
  const size_t SZ = (size_t)BL * 64;              // 1M floats
  const size_t CH = (size_t)B_ * E_ * NCH * 64;   // 512K floats
  float* xp_pre = ws + 0 * SZ;
  float* resT   = ws + 1 * SZ;
  float* xpT    = ws + 2 * SZ;
  float* deltaT = ws + 3 * SZ;
  u32*   BCm    = (u32*)(ws + 4 * SZ);            // packed B|C<<16, SZ u32s
  float* ygT    = ws + 5 * SZ;
  float* Ssum   = ws + 6 * SZ;
  float* Pp     = ws + 6 * SZ + 1 * CH;
  unsigned short* WFT = (unsigned short*)(ws + 6 * SZ + 2 * CH);

  hipLaunchKernelGGL(k_wfuse,    dim3(192),               dim3(64),  0, stream, Wx, Wdt, WFT);
  hipLaunchKernelGGL(k_gemm_in,  dim3(BL / 32),           dim3(256), 0, stream, x, Win, xp_pre, resT);
  hipLaunchKernelGGL(k_fused,    dim3(BL / 64),           dim3(256), 0, stream,
                     xp_pre, conv_w, conv_b, WFT, bdt, xpT, deltaT, BCm);
  hipLaunchKernelGGL(k_scan1,    dim3(B_ * E_ * NCH / 4), dim3(256), 0, stream,
                     deltaT, xpT, BCm, A_log, Ssum, Pp);
  hipLaunchKernelGGL(k_scan3,    dim3(B_ * E_ * NCH / 4), dim3(256), 0, stream,
                     deltaT, xpT, resT, BCm, A_log, Dp, Ssum, Pp, ygT);
  hipLaunchKernelGGL(k_gemm_out, dim3(1024),              dim3(128), 0, stream, ygT, Wout, out);
}

// Round 4
// 171.273 us; speedup vs baseline: 1.2465x; 1.1013x over previous
//
#include <hip/hip_runtime.h>
#include <hip/hip_bf16.h>

#define B_ 8
#define L_ 2048
#define DM 512
#define E_ 64
#define H_ 64
#define R_ 4
#define KC 3
#define BL (B_*L_)   // 16384
#define NX 132       // R + 2H
#define LC 128       // scan chunk length
#define NCH (L_/LC)  // 16 chunks

typedef __attribute__((ext_vector_type(8))) short bfrag;
typedef __attribute__((ext_vector_type(4))) float facc;
typedef unsigned int u32;

#define LOG2E 1.4426950408889634f

__device__ __forceinline__ unsigned short f2b(float f) {
  __hip_bfloat16 h = __float2bfloat16(f);
  return *reinterpret_cast<unsigned short*>(&h);
}
__device__ __forceinline__ float b2f16(unsigned short u) {
  return __uint_as_float((unsigned)u << 16);
}
__device__ __forceinline__ bfrag ld_frag(const unsigned short* p) {
  bfrag t;
  __builtin_memcpy(&t, p, 16);
  return t;
}

// ---- K0: fold W_dt into W_x -> WFT bf16 [192][64] (n-major). 192 blocks x 64 thr.
__global__ __launch_bounds__(64) void k_wfuse(
    const float* __restrict__ Wx, const float* __restrict__ Wdt,
    unsigned short* __restrict__ WFT)
{
  const int n = blockIdx.x;
  const int e = threadIdx.x;
  float v;
  if (n < 64) {
    v = 0.f;
    #pragma unroll
    for (int j = 0; j < R_; ++j)
      v = fmaf(Wx[e * NX + j], Wdt[j * 64 + n], v);
  } else if (n < 128) {
    v = Wx[e * NX + R_ + (n - 64)];
  } else {
    v = Wx[e * NX + R_ + 64 + (n - 128)];
  }
  WFT[n * 64 + e] = f2b(v);
}

// ---- K1 (MFMA, M=32, BK=64, single LDS buffer, 2 barriers/iter):
// xz = x @ W_in ; cols 0..63 -> xp_pre[token][64], 64..127 -> resT
// B staged transposed (n-major) with lane-coalesced column reads + ushort4 stores.
__global__ __launch_bounds__(256) void k_gemm_in(
    const float* __restrict__ x, const float* __restrict__ Win,
    float* __restrict__ xp_pre, float* __restrict__ resT)
{
  __shared__ unsigned short As[32][72];    // 32 rows x 64 k (pad to 144B rows)
  __shared__ unsigned short Bs[128][72];   // 128 n  x 64 k
  const int tid  = threadIdx.x;
  const int m0   = blockIdx.x * 32;
  const int b    = m0 >> 11;
  const int l0   = m0 & 2047;
  const int lane = tid & 63;
  const int wave = tid >> 6;
  const int mt   = wave & 1;
  const int ng   = wave >> 1;
  const int nl   = lane & 15;
  const int g    = lane >> 4;
  // A staging: thread -> (row ar, 8 k at aq*8)
  const int ar = tid >> 3;
  const int aq = tid & 7;
  // B staging: thread -> (col n = bn, 32 k at kq*32)
  const int bn = tid & 127;
  const int kq = tid >> 7;

  facc acc[4];
  #pragma unroll
  for (int j = 0; j < 4; ++j) acc[j] = (facc)(0.f);

  for (int it = 0; it < 8; ++it) {
    const int k0 = it * 64;
    if (it) __syncthreads();
    // stage A: 32 x 64 f32 -> bf16
    #pragma unroll
    for (int p = 0; p < 2; ++p) {
      float4 v = *(const float4*)&x[(size_t)(m0 + ar) * DM + k0 + aq * 8 + 4 * p];
      ushort4 u;
      u.x = f2b(v.x); u.y = f2b(v.y); u.z = f2b(v.z); u.w = f2b(v.w);
      *(ushort4*)&As[ar][aq * 8 + 4 * p] = u;
    }
    // stage B transposed: lane reads a Win column (stride-128 scalars, coalesced
    // across lanes), packs 4 k's into one ushort4 store
    #pragma unroll
    for (int p = 0; p < 8; ++p) {
      const float* wp = &Win[(size_t)(k0 + kq * 32 + 4 * p) * 128 + bn];
      ushort4 u;
      u.x = f2b(wp[0]);
      u.y = f2b(wp[128]);
      u.z = f2b(wp[256]);
      u.w = f2b(wp[384]);
      *(ushort4*)&Bs[bn][kq * 32 + 4 * p] = u;
    }
    __syncthreads();
    #pragma unroll
    for (int ks = 0; ks < 2; ++ks) {
      bfrag af = ld_frag(&As[mt * 16 + nl][ks * 32 + g * 8]);
      #pragma unroll
      for (int nt2 = 0; nt2 < 4; ++nt2) {
        bfrag bfr = ld_frag(&Bs[(ng * 4 + nt2) * 16 + nl][ks * 32 + g * 8]);
        acc[nt2] = __builtin_amdgcn_mfma_f32_16x16x32_bf16(af, bfr, acc[nt2], 0, 0, 0);
      }
    }
  }
  #pragma unroll
  for (int nt2 = 0; nt2 < 4; ++nt2) {
    facc a = acc[nt2];
    int c = (ng * 4 + nt2) * 16 + nl;
    int mrow = mt * 16 + 4 * g;
    if (c < 64) {
      #pragma unroll
      for (int r = 0; r < 4; ++r)
        xp_pre[(size_t)(m0 + mrow + r) * 64 + c] = a[r];
    } else {
      *(float4*)&resT[(size_t)(b * 64 + (c - 64)) * L_ + l0 + mrow] =
          make_float4(a[0], a[1], a[2], a[3]);
    }
  }
}

// ---- K2 (fused, MFMA — single-shot staging, 2 barriers, no re-staging):
// conv+silu -> xpT + bf16 A-tile ; [delta|B|C] = xp @ WF ; softplus -> deltaT ;
// B and C packed into one u32 per (token,h): low = B bf16 bits, high = C bf16 bits.
__global__ __launch_bounds__(256) void k_fused(
    const float* __restrict__ xp_pre,
    const float* __restrict__ conv_w, const float* __restrict__ conv_b,
    const unsigned short* __restrict__ WFT, const float* __restrict__ bdt,
    float* __restrict__ xpT, float* __restrict__ deltaT,
    u32* __restrict__ BCm)
{
  __shared__ float raw[66][65];
  __shared__ unsigned short rawb[64][72];     // 144B rows, 16B aligned
  __shared__ unsigned short WFb[192][72];     // FULL K=64 rows: no aliasing, staged ONCE
  const int tid = threadIdx.x;
  const int t0 = blockIdx.x * 64;
  const int b  = t0 >> 11;
  const int l0 = t0 & 2047;
  // stage raw (zero-pad l<0)
  for (int fidx = tid; fidx < 66 * 16; fidx += 256) {
    int r = fidx >> 4, cg = fidx & 15;
    int l = l0 - 2 + r;
    float4 v = make_float4(0.f, 0.f, 0.f, 0.f);
    if (l >= 0) v = *(const float4*)&xp_pre[((size_t)b * L_ + l) * 64 + cg * 4];
    raw[r][cg * 4 + 0] = v.x;
    raw[r][cg * 4 + 1] = v.y;
    raw[r][cg * 4 + 2] = v.z;
    raw[r][cg * 4 + 3] = v.w;
  }
  // stage full WFb (192 rows x 64 k), ushort4 chunks; offsets 4*jq <= 60 < 72
  for (int i4 = tid; i4 < 192 * 16; i4 += 256) {
    int n = i4 >> 4, jq = i4 & 15;
    *(ushort4*)&WFb[n][jq * 4] = *(const ushort4*)&WFT[n * 64 + jq * 4];
  }
  __syncthreads();
  // conv + silu: thread -> (e, 16 tokens); write bf16 A-tile + xpT
  const int e  = tid & 63;
  const int tl = tid >> 6;
  const float w0 = conv_w[e * KC + 0], w1 = conv_w[e * KC + 1], w2 = conv_w[e * KC + 2];
  const float cb = conv_b[e];
  float cres[16];
  #pragma unroll
  for (int i = 0; i < 16; ++i) {
    int tok = tl * 16 + i;
    float a = cb;
    a = fmaf(raw[tok + 0][e], w0, a);
    a = fmaf(raw[tok + 1][e], w1, a);
    a = fmaf(raw[tok + 2][e], w2, a);
    cres[i] = a / (1.f + __expf(-a));
  }
  #pragma unroll
  for (int i = 0; i < 16; ++i) rawb[tl * 16 + i][e] = f2b(cres[i]);
  #pragma unroll
  for (int i = 0; i < 16; i += 4)
    *(float4*)&xpT[(size_t)(b * 64 + e) * L_ + l0 + tl * 16 + i] =
        make_float4(cres[i], cres[i + 1], cres[i + 2], cres[i + 3]);
  __syncthreads();
  // MFMA GEMM: M=64 (4 waves), N=192 (12 tiles), K=64 (2 ksteps) — all LDS read-only now
  const int wave = tid >> 6;
  const int lane = tid & 63;
  const int nl   = lane & 15;
  const int g    = lane >> 4;
  facc acc[12];
  #pragma unroll
  for (int j = 0; j < 12; ++j) acc[j] = (facc)(0.f);
  #pragma unroll
  for (int ks = 0; ks < 2; ++ks) {
    bfrag af = ld_frag(&rawb[wave * 16 + nl][ks * 32 + g * 8]);
    #pragma unroll
    for (int nt = 0; nt < 12; ++nt) {
      bfrag bfr = ld_frag(&WFb[nt * 16 + nl][ks * 32 + g * 8]);
      acc[nt] = __builtin_amdgcn_mfma_f32_16x16x32_bf16(af, bfr, acc[nt], 0, 0, 0);
    }
  }
  const int mrow = wave * 16 + 4 * g;
  // delta cols (0..63): softplus -> deltaT (transposed, coalesced)
  #pragma unroll
  for (int nt = 0; nt < 4; ++nt) {
    facc a = acc[nt];
    int c = nt * 16 + nl;
    float bias = bdt[c];
    float d0 = a[0] + bias, d1 = a[1] + bias, d2 = a[2] + bias, d3 = a[3] + bias;
    float4 dv;
    dv.x = (d0 > 20.f) ? d0 : log1pf(__expf(d0));
    dv.y = (d1 > 20.f) ? d1 : log1pf(__expf(d1));
    dv.z = (d2 > 20.f) ? d2 : log1pf(__expf(d2));
    dv.w = (d3 > 20.f) ? d3 : log1pf(__expf(d3));
    *(float4*)&deltaT[(size_t)(b * 64 + c) * L_ + l0 + mrow] = dv;
  }
  // B (nt 4..7) pairs with C (nt+4 = 8..11) at the same (row, col) -> pack u32
  #pragma unroll
  for (int nt = 4; nt < 8; ++nt) {
    facc aB = acc[nt];
    facc aC = acc[nt + 4];
    int col = (nt - 4) * 16 + nl;
    #pragma unroll
    for (int r = 0; r < 4; ++r)
      BCm[(size_t)(t0 + mrow + r) * 64 + col] =
          (u32)f2b(aB[r]) | ((u32)f2b(aC[r]) << 16);
  }
}

// ---- K3a: per-chunk summaries. 4 waves/block, wave-private LDS, no barriers.
// Whole chunk (128 tokens) staged once; w = d*x precomputed; exp folded to exp2.
__global__ __launch_bounds__(256) void k_scan1(
    const float* __restrict__ deltaT, const float* __restrict__ xpT,
    const u32* __restrict__ BCm, const float* __restrict__ A_log,
    float* __restrict__ Ssum, float* __restrict__ Pp)
{
  __shared__ float dwA[4][256];   // per wave: d[0..127], w[128..255]
  const int tid = threadIdx.x;
  const int wv  = tid >> 6;
  const int h   = tid & 63;
  const int id  = blockIdx.x * 4 + wv;
  const int c   = id & (NCH - 1);
  if (c == NCH - 1) return;       // last chunk's summary is never consumed
  const int e = (id >> 4) & 63;
  const int b = id >> 10;
  const float A2 = -__expf(A_log[e * 64 + h]) * LOG2E;   // A * log2(e)
  const size_t beL = (size_t)(b * 64 + e) * L_;
  const int l0 = c * LC;
  float* dw = dwA[wv];
  {
    float2 dv = *(const float2*)&deltaT[beL + l0 + 2 * h];
    float2 xv = *(const float2*)&xpT[beL + l0 + 2 * h];
    *(float2*)&dw[2 * h] = dv;
    *(float2*)&dw[128 + 2 * h] = make_float2(dv.x * xv.x, dv.y * xv.y);
  }
  const u32* bc = &BCm[(size_t)(b * L_ + l0) * 64 + h];
  float s = 0.f, sd = 0.f;
  #pragma unroll 2
  for (int k16 = 0; k16 < 8; ++k16) {
    #pragma unroll
    for (int kk = 0; kk < 16; ++kk) {
      const int k = k16 * 16 + kk;
      float dlt = dw[k];
      float w   = dw[128 + k];
      u32 u = bc[(size_t)k * 64];
      float Bh = __uint_as_float(u << 16);
      s = fmaf(__builtin_amdgcn_exp2f(dlt * A2), s, w * Bh);
      sd += dlt;
    }
  }
  const size_t idx = (size_t)id * 64 + h;
  Ssum[idx] = s;
  Pp[idx]   = __builtin_amdgcn_exp2f(A2 * sd);
}

// ---- K3c: scan per chunk. 4 waves/block, wave-private LDS, no barriers.
// Entry state composed inline; f32 tile reduce (no bf16 roundtrip); packed BC loads.
__global__ __launch_bounds__(256) void k_scan3(
    const float* __restrict__ deltaT, const float* __restrict__ xpT,
    const float* __restrict__ resT, const u32* __restrict__ BCm,
    const float* __restrict__ A_log, const float* __restrict__ Dp,
    const float* __restrict__ Ssum, const float* __restrict__ Pp,
    float* __restrict__ ygT)
{
  __shared__ float tileA[4][16][68];
  __shared__ float bufA[4][512];  // d[0..127] w[128..255] x[256..383] res[384..511]
  const int tid = threadIdx.x;
  const int wv  = tid >> 6;
  const int h   = tid & 63;
  const int id  = blockIdx.x * 4 + wv;
  const int c   = id & (NCH - 1);
  const int e   = (id >> 4) & 63;
  const int b   = id >> 10;
  const float A2 = -__expf(A_log[e * 64 + h]) * LOG2E;
  const float Dv = Dp[e];
  const size_t beL = (size_t)(b * 64 + e) * L_;
  float (*tile)[68] = tileA[wv];
  float* buf = bufA[wv];
  // compose entry state from chunk summaries 0..c-1 (global reads only)
  float s = 0.f;
  const size_t sbase = (size_t)(id & ~(NCH - 1)) * 64 + h;
  for (int cc = 0; cc < c; ++cc)
    s = fmaf(Pp[sbase + (size_t)cc * 64], s, Ssum[sbase + (size_t)cc * 64]);
  const int l0 = c * LC;
  {
    float2 dv = *(const float2*)&deltaT[beL + l0 + 2 * h];
    float2 xv = *(const float2*)&xpT[beL + l0 + 2 * h];
    float2 rv = *(const float2*)&resT[beL + l0 + 2 * h];
    *(float2*)&buf[2 * h]       = dv;
    *(float2*)&buf[128 + 2 * h] = make_float2(dv.x * xv.x, dv.y * xv.y);
    *(float2*)&buf[256 + 2 * h] = xv;
    *(float2*)&buf[384 + 2 * h] = rv;
  }
  const u32* bc = &BCm[(size_t)(b * L_ + l0) * 64 + h];
  const int r = h & 15, q = h >> 4;
  #pragma unroll 2
  for (int k16 = 0; k16 < 8; ++k16) {
    #pragma unroll
    for (int kk = 0; kk < 16; ++kk) {
      const int k = k16 * 16 + kk;
      float dlt = buf[k];
      float w   = buf[128 + k];
      u32 u = bc[(size_t)k * 64];
      s = fmaf(__builtin_amdgcn_exp2f(dlt * A2), s, w * __uint_as_float(u << 16));
      tile[kk][h] = s * __uint_as_float(u & 0xffff0000u);
    }
    // lane h: row r = h&15, quarter q = h>>4; sum 16 f32 then combine quarters
    float part = 0.f;
    const float4* rp = (const float4*)&tile[r][q * 16];
    #pragma unroll
    for (int jq = 0; jq < 4; ++jq) {
      float4 v = rp[jq];
      part += (v.x + v.y) + (v.z + v.w);
    }
    part += __shfl_xor(part, 16, 64);
    part += __shfl_xor(part, 32, 64);
    if (q == 0) {
      const int lk = k16 * 16 + r;
      float y = fmaf(buf[256 + lk], Dv, part);
      y *= __builtin_amdgcn_rcpf(1.f + __builtin_amdgcn_exp2f(-LOG2E * buf[384 + lk]));
      ygT[beL + l0 + lk] = y;
    }
  }
}

// ---- K4 (MFMA): out = ygT^T @ W_out. Single-shot staging + 1 barrier. 1024 blocks x 128 thr.
__global__ __launch_bounds__(128) void k_gemm_out(
    const float* __restrict__ ygT, const float* __restrict__ Wout,
    float* __restrict__ out)
{
  __shared__ unsigned short As[64][68];
  __shared__ unsigned short Bs[128][68];
  const int tid  = threadIdx.x;
  const int m0   = (blockIdx.x & 255) * 64;
  const int n0   = (blockIdx.x >> 8) * 128;
  const int b    = m0 >> 11;
  const int l0   = m0 & 2047;
  const int lane = tid & 63;
  const int wave = tid >> 6;
  const int nl   = lane & 15;
  const int g    = lane >> 4;
  #pragma unroll
  for (int p = 0; p < 8; ++p) {
    int fidx = tid + 128 * p;              // 0..1023
    int e = fidx >> 4, q = fidx & 15;
    float4 v = *(const float4*)&ygT[(size_t)(b * 64 + e) * L_ + l0 + 4 * q];
    As[4 * q + 0][e] = f2b(v.x);
    As[4 * q + 1][e] = f2b(v.y);
    As[4 * q + 2][e] = f2b(v.z);
    As[4 * q + 3][e] = f2b(v.w);
  }
  #pragma unroll
  for (int p = 0; p < 16; ++p) {
    int fidx = tid + 128 * p;
    int r = fidx >> 5, cq = fidx & 31;
    float4 v = *(const float4*)&Wout[(size_t)r * DM + n0 + 4 * cq];
    Bs[4 * cq + 0][r] = f2b(v.x);
    Bs[4 * cq + 1][r] = f2b(v.y);
    Bs[4 * cq + 2][r] = f2b(v.z);
    Bs[4 * cq + 3][r] = f2b(v.w);
  }
  __syncthreads();
  facc acc[2][8];
  #pragma unroll
  for (int i = 0; i < 2; ++i)
    #pragma unroll
    for (int j = 0; j < 8; ++j)
      acc[i][j] = (facc)(0.f);
  #pragma unroll
  for (int ks = 0; ks < 2; ++ks) {
    bfrag af0 = ld_frag(&As[wave * 32 + nl][ks * 32 + g * 8]);
    bfrag af1 = ld_frag(&As[wave * 32 + 16 + nl][ks * 32 + g * 8]);
    #pragma unroll
    for (int nt = 0; nt < 8; ++nt) {
      bfrag bfr = ld_frag(&Bs[nt * 16 + nl][ks * 32 + g * 8]);
      acc[0][nt] = __builtin_amdgcn_mfma_f32_16x16x32_bf16(af0, bfr, acc[0][nt], 0, 0, 0);
      acc[1][nt] = __builtin_amdgcn_mfma_f32_16x16x32_bf16(af1, bfr, acc[1][nt], 0, 0, 0);
    }
  }
  #pragma unroll
  for (int mt = 0; mt < 2; ++mt) {
    int mrow = m0 + wave * 32 + mt * 16 + 4 * g;
    #pragma unroll
    for (int nt = 0; nt < 8; ++nt) {
      facc a = acc[mt][nt];
      int c = n0 + nt * 16 + nl;
      #pragma unroll
      for (int r = 0; r < 4; ++r)
        out[(size_t)(mrow + r) * DM + c] = a[r];
    }
  }
}

extern "C" void kernel_launch(void* const* d_in, const int* in_sizes, int n_in,
                              void* d_out, int out_size, void* d_ws, size_t ws_size,
                              hipStream_t stream) {
  const float* x      = (const float*)d_in[0];
  const float* Win    = (const float*)d_in[1];
  const float* conv_w = (const float*)d_in[2];
  const float* conv_b = (const float*)d_in[3];
  const float* Wx     = (const float*)d_in[4];
  const float* Wdt    = (const float*)d_in[5];
  const float* bdt    = (const float*)d_in[6];
  const float* A_log  = (const float*)d_in[7];
  const float* Dp     = (const float*)d_in[8];
  const float* Wout   = (const float*)d_in[9];
  float* out = (float*)d_out;

  float* ws = (float*)d_ws;
  const size_t SZ = (size_t)BL * 64;              // 1M floats
  const size_t CH = (size_t)B_ * E_ * NCH * 64;   // 512K floats
  float* xp_pre = ws + 0 * SZ;
  float* resT   = ws + 1 * SZ;
  float* xpT    = ws + 2 * SZ;
  float* deltaT = ws + 3 * SZ;
  u32*   BCm    = (u32*)(ws + 4 * SZ);            // packed B|C<<16, SZ u32s
  float* ygT    = ws + 5 * SZ;
  float* Ssum   = ws + 6 * SZ;
  float* Pp     = ws + 6 * SZ + 1 * CH;
  unsigned short* WFT = (unsigned short*)(ws + 6 * SZ + 2 * CH);

  hipLaunchKernelGGL(k_wfuse,    dim3(192),               dim3(64),  0, stream, Wx, Wdt, WFT);
  hipLaunchKernelGGL(k_gemm_in,  dim3(BL / 32),           dim3(256), 0, stream,
                     x, Win, xp_pre, resT);
  hipLaunchKernelGGL(k_fused,    dim3(BL / 64),           dim3(256), 0, stream,
                     xp_pre, conv_w, conv_b, WFT, bdt, xpT, deltaT, BCm);
  hipLaunchKernelGGL(k_scan1,    dim3(B_ * E_ * NCH / 4), dim3(256), 0, stream,
                     deltaT, xpT, BCm, A_log, Ssum, Pp);
  hipLaunchKernelGGL(k_scan3,    dim3(B_ * E_ * NCH / 4), dim3(256), 0, stream,
                     deltaT, xpT, resT, BCm, A_log, Dp, Ssum, Pp, ygT);
  hipLaunchKernelGGL(k_gemm_out, dim3(1024),              dim3(128), 0, stream, ygT, Wout, out);
}

// Round 5
// 170.424 us; speedup vs baseline: 1.2527x; 1.0050x over previous
//
#include <hip/hip_runtime.h>
#include <hip/hip_bf16.h>

#define B_ 8
#define L_ 2048
#define DM 512
#define E_ 64
#define H_ 64
#define R_ 4
#define KC 3
#define BL (B_*L_)   // 16384
#define NX 132       // R + 2H
#define LC 128       // scan chunk length
#define NCH (L_/LC)  // 16 chunks

typedef __attribute__((ext_vector_type(8))) short bfrag;
typedef __attribute__((ext_vector_type(4))) float facc;
typedef unsigned int u32;

#define LOG2E 1.4426950408889634f

__device__ __forceinline__ unsigned short f2b(float f) {
  __hip_bfloat16 h = __float2bfloat16(f);
  return *reinterpret_cast<unsigned short*>(&h);
}
__device__ __forceinline__ float b2f16(unsigned short u) {
  return __uint_as_float((unsigned)u << 16);
}
__device__ __forceinline__ bfrag ld_frag(const unsigned short* p) {
  bfrag t;
  __builtin_memcpy(&t, p, 16);
  return t;
}

// ---- K0: fold W_dt into W_x -> WFT bf16 [192][64] (n-major); blocks 192..255:
// elementwise Win f32 -> WinTk bf16 (same [512][128] layout).
__global__ __launch_bounds__(64) void k_wfuse(
    const float* __restrict__ Wx, const float* __restrict__ Wdt,
    const float* __restrict__ Win,
    unsigned short* __restrict__ WFT, unsigned short* __restrict__ WinTk)
{
  if (blockIdx.x >= 192) {
    const int gid = (blockIdx.x - 192) * 64 + threadIdx.x;   // 0..4095
    const float4* src = (const float4*)Win;
    #pragma unroll
    for (int i = gid; i < DM * 128 / 4; i += 4096) {
      float4 v = src[i];
      ushort4 u;
      u.x = f2b(v.x); u.y = f2b(v.y); u.z = f2b(v.z); u.w = f2b(v.w);
      *(ushort4*)&WinTk[i * 4] = u;
    }
    return;
  }
  const int n = blockIdx.x;
  const int e = threadIdx.x;
  float v;
  if (n < 64) {
    v = 0.f;
    #pragma unroll
    for (int j = 0; j < R_; ++j)
      v = fmaf(Wx[e * NX + j], Wdt[j * 64 + n], v);
  } else if (n < 128) {
    v = Wx[e * NX + R_ + (n - 64)];
  } else {
    v = Wx[e * NX + R_ + 64 + (n - 128)];
  }
  WFT[n * 64 + e] = f2b(v);
}

// ---- K1 (MFMA, M=32, BK=64, single LDS buffer, 2 barriers/iter):
// xz = x @ W_in ; cols 0..63 -> xp_pre[token][64], 64..127 -> resT
// B staged transposed from pre-converted bf16 WinTk (no in-kernel f2b for B).
__global__ __launch_bounds__(256) void k_gemm_in(
    const float* __restrict__ x, const unsigned short* __restrict__ WinTk,
    float* __restrict__ xp_pre, float* __restrict__ resT)
{
  __shared__ unsigned short As[32][72];    // 32 rows x 64 k (pad to 144B rows)
  __shared__ unsigned short Bs[128][72];   // 128 n  x 64 k
  const int tid  = threadIdx.x;
  const int m0   = blockIdx.x * 32;
  const int b    = m0 >> 11;
  const int l0   = m0 & 2047;
  const int lane = tid & 63;
  const int wave = tid >> 6;
  const int mt   = wave & 1;
  const int ng   = wave >> 1;
  const int nl   = lane & 15;
  const int g    = lane >> 4;
  // A staging: thread -> (row ar, 8 k at aq*8)
  const int ar = tid >> 3;
  const int aq = tid & 7;
  // B staging: thread -> (col n = bn, 32 k at kq*32)
  const int bn = tid & 127;
  const int kq = tid >> 7;

  facc acc[4];
  #pragma unroll
  for (int j = 0; j < 4; ++j) acc[j] = (facc)(0.f);

  for (int it = 0; it < 8; ++it) {
    const int k0 = it * 64;
    if (it) __syncthreads();
    // stage A: 32 x 64 f32 -> bf16
    #pragma unroll
    for (int p = 0; p < 2; ++p) {
      float4 v = *(const float4*)&x[(size_t)(m0 + ar) * DM + k0 + aq * 8 + 4 * p];
      ushort4 u;
      u.x = f2b(v.x); u.y = f2b(v.y); u.z = f2b(v.z); u.w = f2b(v.w);
      *(ushort4*)&As[ar][aq * 8 + 4 * p] = u;
    }
    // stage B transposed: lane reads 4 k's of column bn from bf16 WinTk
    // (2B loads, lane-consecutive n -> coalesced), packs, stores uint2
    #pragma unroll
    for (int p = 0; p < 8; ++p) {
      const unsigned short* wp = &WinTk[(size_t)(k0 + kq * 32 + 4 * p) * 128 + bn];
      u32 lo = (u32)wp[0]   | ((u32)wp[128] << 16);
      u32 hi = (u32)wp[256] | ((u32)wp[384] << 16);
      uint2 uu; uu.x = lo; uu.y = hi;
      *(uint2*)&Bs[bn][kq * 32 + 4 * p] = uu;
    }
    __syncthreads();
    #pragma unroll
    for (int ks = 0; ks < 2; ++ks) {
      bfrag af = ld_frag(&As[mt * 16 + nl][ks * 32 + g * 8]);
      #pragma unroll
      for (int nt2 = 0; nt2 < 4; ++nt2) {
        bfrag bfr = ld_frag(&Bs[(ng * 4 + nt2) * 16 + nl][ks * 32 + g * 8]);
        acc[nt2] = __builtin_amdgcn_mfma_f32_16x16x32_bf16(af, bfr, acc[nt2], 0, 0, 0);
      }
    }
  }
  #pragma unroll
  for (int nt2 = 0; nt2 < 4; ++nt2) {
    facc a = acc[nt2];
    int c = (ng * 4 + nt2) * 16 + nl;
    int mrow = mt * 16 + 4 * g;
    if (c < 64) {
      #pragma unroll
      for (int r = 0; r < 4; ++r)
        xp_pre[(size_t)(m0 + mrow + r) * 64 + c] = a[r];
    } else {
      *(float4*)&resT[(size_t)(b * 64 + (c - 64)) * L_ + l0 + mrow] =
          make_float4(a[0], a[1], a[2], a[3]);
    }
  }
}

// ---- K2 (fused, MFMA): grid 512 — each 64-token group split across 2 blocks:
// yh=0: delta tiles 0..3 (+ xpT write); yh=1: B tiles 4..7 + C tiles 8..11 (packed).
// Conv duplicated in both blocks (cheap); doubles CU-level parallelism.
__global__ __launch_bounds__(256) void k_fused(
    const float* __restrict__ xp_pre,
    const float* __restrict__ conv_w, const float* __restrict__ conv_b,
    const unsigned short* __restrict__ WFT, const float* __restrict__ bdt,
    float* __restrict__ xpT, float* __restrict__ deltaT,
    u32* __restrict__ BCm)
{
  __shared__ float raw[66][65];
  __shared__ unsigned short rawb[64][72];     // 144B rows, 16B aligned
  __shared__ unsigned short WFb[192][72];     // staged half per block
  const int tid = threadIdx.x;
  const int grp = blockIdx.x >> 1;
  const int yh  = blockIdx.x & 1;
  const int t0 = grp * 64;
  const int b  = t0 >> 11;
  const int l0 = t0 & 2047;
  // stage raw (zero-pad l<0)
  for (int fidx = tid; fidx < 66 * 16; fidx += 256) {
    int r = fidx >> 4, cg = fidx & 15;
    int l = l0 - 2 + r;
    float4 v = make_float4(0.f, 0.f, 0.f, 0.f);
    if (l >= 0) v = *(const float4*)&xp_pre[((size_t)b * L_ + l) * 64 + cg * 4];
    raw[r][cg * 4 + 0] = v.x;
    raw[r][cg * 4 + 1] = v.y;
    raw[r][cg * 4 + 2] = v.z;
    raw[r][cg * 4 + 3] = v.w;
  }
  // stage the WFb rows this block needs: yh=0 -> rows 0..63; yh=1 -> rows 64..191
  {
    const int nbase = yh ? 64 : 0;
    const int nrows = yh ? 128 : 64;
    for (int i4 = tid; i4 < nrows * 16; i4 += 256) {
      int n = nbase + (i4 >> 4), jq = i4 & 15;
      *(ushort4*)&WFb[n][jq * 4] = *(const ushort4*)&WFT[n * 64 + jq * 4];
    }
  }
  __syncthreads();
  // conv + silu: thread -> (e, 16 tokens); write bf16 A-tile (+ xpT if yh==0)
  const int e  = tid & 63;
  const int tl = tid >> 6;
  const float w0 = conv_w[e * KC + 0], w1 = conv_w[e * KC + 1], w2 = conv_w[e * KC + 2];
  const float cb = conv_b[e];
  float cres[16];
  #pragma unroll
  for (int i = 0; i < 16; ++i) {
    int tok = tl * 16 + i;
    float a = cb;
    a = fmaf(raw[tok + 0][e], w0, a);
    a = fmaf(raw[tok + 1][e], w1, a);
    a = fmaf(raw[tok + 2][e], w2, a);
    cres[i] = a / (1.f + __expf(-a));
  }
  #pragma unroll
  for (int i = 0; i < 16; ++i) rawb[tl * 16 + i][e] = f2b(cres[i]);
  if (yh == 0) {
    #pragma unroll
    for (int i = 0; i < 16; i += 4)
      *(float4*)&xpT[(size_t)(b * 64 + e) * L_ + l0 + tl * 16 + i] =
          make_float4(cres[i], cres[i + 1], cres[i + 2], cres[i + 3]);
  }
  __syncthreads();
  // MFMA GEMM: M=64 (4 waves x 16 rows), K=64 (2 ksteps); N-tiles split by yh.
  const int wave = tid >> 6;
  const int lane = tid & 63;
  const int nl   = lane & 15;
  const int g    = lane >> 4;
  const int mrow = wave * 16 + 4 * g;
  if (yh == 0) {
    facc acc[4];
    #pragma unroll
    for (int j = 0; j < 4; ++j) acc[j] = (facc)(0.f);
    #pragma unroll
    for (int ks = 0; ks < 2; ++ks) {
      bfrag af = ld_frag(&rawb[wave * 16 + nl][ks * 32 + g * 8]);
      #pragma unroll
      for (int nt = 0; nt < 4; ++nt) {
        bfrag bfr = ld_frag(&WFb[nt * 16 + nl][ks * 32 + g * 8]);
        acc[nt] = __builtin_amdgcn_mfma_f32_16x16x32_bf16(af, bfr, acc[nt], 0, 0, 0);
      }
    }
    // delta cols (0..63): softplus -> deltaT (transposed, coalesced)
    #pragma unroll
    for (int nt = 0; nt < 4; ++nt) {
      facc a = acc[nt];
      int c = nt * 16 + nl;
      float bias = bdt[c];
      float d0 = a[0] + bias, d1 = a[1] + bias, d2 = a[2] + bias, d3 = a[3] + bias;
      float4 dv;
      dv.x = (d0 > 20.f) ? d0 : log1pf(__expf(d0));
      dv.y = (d1 > 20.f) ? d1 : log1pf(__expf(d1));
      dv.z = (d2 > 20.f) ? d2 : log1pf(__expf(d2));
      dv.w = (d3 > 20.f) ? d3 : log1pf(__expf(d3));
      *(float4*)&deltaT[(size_t)(b * 64 + c) * L_ + l0 + mrow] = dv;
    }
  } else {
    facc acc[8];
    #pragma unroll
    for (int j = 0; j < 8; ++j) acc[j] = (facc)(0.f);
    #pragma unroll
    for (int ks = 0; ks < 2; ++ks) {
      bfrag af = ld_frag(&rawb[wave * 16 + nl][ks * 32 + g * 8]);
      #pragma unroll
      for (int j = 0; j < 8; ++j) {
        bfrag bfr = ld_frag(&WFb[(4 + j) * 16 + nl][ks * 32 + g * 8]);
        acc[j] = __builtin_amdgcn_mfma_f32_16x16x32_bf16(af, bfr, acc[j], 0, 0, 0);
      }
    }
    // B (acc 0..3, tiles 4..7) pairs with C (acc 4..7, tiles 8..11) -> pack u32
    #pragma unroll
    for (int j = 0; j < 4; ++j) {
      facc aB = acc[j];
      facc aC = acc[4 + j];
      int col = j * 16 + nl;
      #pragma unroll
      for (int r = 0; r < 4; ++r)
        BCm[(size_t)(t0 + mrow + r) * 64 + col] =
            (u32)f2b(aB[r]) | ((u32)f2b(aC[r]) << 16);
    }
  }
}

// ---- K3a: per-chunk summaries. 4 waves/block, wave-private LDS, no barriers.
__global__ __launch_bounds__(256) void k_scan1(
    const float* __restrict__ deltaT, const float* __restrict__ xpT,
    const u32* __restrict__ BCm, const float* __restrict__ A_log,
    float* __restrict__ Ssum, float* __restrict__ Pp)
{
  __shared__ float dwA[4][256];   // per wave: d[0..127], w[128..255]
  const int tid = threadIdx.x;
  const int wv  = tid >> 6;
  const int h   = tid & 63;
  const int id  = blockIdx.x * 4 + wv;
  const int c   = id & (NCH - 1);
  if (c == NCH - 1) return;       // last chunk's summary is never consumed
  const int e = (id >> 4) & 63;
  const int b = id >> 10;
  const float A2 = -__expf(A_log[e * 64 + h]) * LOG2E;   // A * log2(e)
  const size_t beL = (size_t)(b * 64 + e) * L_;
  const int l0 = c * LC;
  float* dw = dwA[wv];
  {
    float2 dv = *(const float2*)&deltaT[beL + l0 + 2 * h];
    float2 xv = *(const float2*)&xpT[beL + l0 + 2 * h];
    *(float2*)&dw[2 * h] = dv;
    *(float2*)&dw[128 + 2 * h] = make_float2(dv.x * xv.x, dv.y * xv.y);
  }
  const u32* bc = &BCm[(size_t)(b * L_ + l0) * 64 + h];
  float s = 0.f, sd = 0.f;
  #pragma unroll 2
  for (int k16 = 0; k16 < 8; ++k16) {
    #pragma unroll
    for (int kk = 0; kk < 16; ++kk) {
      const int k = k16 * 16 + kk;
      float dlt = dw[k];
      float w   = dw[128 + k];
      u32 u = bc[(size_t)k * 64];
      float Bh = __uint_as_float(u << 16);
      s = fmaf(__builtin_amdgcn_exp2f(dlt * A2), s, w * Bh);
      sd += dlt;
    }
  }
  const size_t idx = (size_t)id * 64 + h;
  Ssum[idx] = s;
  Pp[idx]   = __builtin_amdgcn_exp2f(A2 * sd);
}

// ---- K3c: scan per chunk. 4 waves/block, wave-private LDS, no barriers.
__global__ __launch_bounds__(256) void k_scan3(
    const float* __restrict__ deltaT, const float* __restrict__ xpT,
    const float* __restrict__ resT, const u32* __restrict__ BCm,
    const float* __restrict__ A_log, const float* __restrict__ Dp,
    const float* __restrict__ Ssum, const float* __restrict__ Pp,
    float* __restrict__ ygT)
{
  __shared__ float tileA[4][16][68];
  __shared__ float bufA[4][512];  // d[0..127] w[128..255] x[256..383] res[384..511]
  const int tid = threadIdx.x;
  const int wv  = tid >> 6;
  const int h   = tid & 63;
  const int id  = blockIdx.x * 4 + wv;
  const int c   = id & (NCH - 1);
  const int e   = (id >> 4) & 63;
  const int b   = id >> 10;
  const float A2 = -__expf(A_log[e * 64 + h]) * LOG2E;
  const float Dv = Dp[e];
  const size_t beL = (size_t)(b * 64 + e) * L_;
  float (*tile)[68] = tileA[wv];
  float* buf = bufA[wv];
  // compose entry state from chunk summaries 0..c-1 (global reads only)
  float s = 0.f;
  const size_t sbase = (size_t)(id & ~(NCH - 1)) * 64 + h;
  for (int cc = 0; cc < c; ++cc)
    s = fmaf(Pp[sbase + (size_t)cc * 64], s, Ssum[sbase + (size_t)cc * 64]);
  const int l0 = c * LC;
  {
    float2 dv = *(const float2*)&deltaT[beL + l0 + 2 * h];
    float2 xv = *(const float2*)&xpT[beL + l0 + 2 * h];
    float2 rv = *(const float2*)&resT[beL + l0 + 2 * h];
    *(float2*)&buf[2 * h]       = dv;
    *(float2*)&buf[128 + 2 * h] = make_float2(dv.x * xv.x, dv.y * xv.y);
    *(float2*)&buf[256 + 2 * h] = xv;
    *(float2*)&buf[384 + 2 * h] = rv;
  }
  const u32* bc = &BCm[(size_t)(b * L_ + l0) * 64 + h];
  const int r = h & 15, q = h >> 4;
  #pragma unroll 2
  for (int k16 = 0; k16 < 8; ++k16) {
    #pragma unroll
    for (int kk = 0; kk < 16; ++kk) {
      const int k = k16 * 16 + kk;
      float dlt = buf[k];
      float w   = buf[128 + k];
      u32 u = bc[(size_t)k * 64];
      s = fmaf(__builtin_amdgcn_exp2f(dlt * A2), s, w * __uint_as_float(u << 16));
      tile[kk][h] = s * __uint_as_float(u & 0xffff0000u);
    }
    // lane h: row r = h&15, quarter q = h>>4; sum 16 f32 then combine quarters
    float part = 0.f;
    const float4* rp = (const float4*)&tile[r][q * 16];
    #pragma unroll
    for (int jq = 0; jq < 4; ++jq) {
      float4 v = rp[jq];
      part += (v.x + v.y) + (v.z + v.w);
    }
    part += __shfl_xor(part, 16, 64);
    part += __shfl_xor(part, 32, 64);
    if (q == 0) {
      const int lk = k16 * 16 + r;
      float y = fmaf(buf[256 + lk], Dv, part);
      y *= __builtin_amdgcn_rcpf(1.f + __builtin_amdgcn_exp2f(-LOG2E * buf[384 + lk]));
      ygT[beL + l0 + lk] = y;
    }
  }
}

// ---- K4 (MFMA): out = ygT^T @ W_out. Single-shot staging + 1 barrier. 1024 blocks x 128 thr.
__global__ __launch_bounds__(128) void k_gemm_out(
    const float* __restrict__ ygT, const float* __restrict__ Wout,
    float* __restrict__ out)
{
  __shared__ unsigned short As[64][68];
  __shared__ unsigned short Bs[128][68];
  const int tid  = threadIdx.x;
  const int m0   = (blockIdx.x & 255) * 64;
  const int n0   = (blockIdx.x >> 8) * 128;
  const int b    = m0 >> 11;
  const int l0   = m0 & 2047;
  const int lane = tid & 63;
  const int wave = tid >> 6;
  const int nl   = lane & 15;
  const int g    = lane >> 4;
  #pragma unroll
  for (int p = 0; p < 8; ++p) {
    int fidx = tid + 128 * p;              // 0..1023
    int e = fidx >> 4, q = fidx & 15;
    float4 v = *(const float4*)&ygT[(size_t)(b * 64 + e) * L_ + l0 + 4 * q];
    As[4 * q + 0][e] = f2b(v.x);
    As[4 * q + 1][e] = f2b(v.y);
    As[4 * q + 2][e] = f2b(v.z);
    As[4 * q + 3][e] = f2b(v.w);
  }
  #pragma unroll
  for (int p = 0; p < 16; ++p) {
    int fidx = tid + 128 * p;
    int r = fidx >> 5, cq = fidx & 31;
    float4 v = *(const float4*)&Wout[(size_t)r * DM + n0 + 4 * cq];
    Bs[4 * cq + 0][r] = f2b(v.x);
    Bs[4 * cq + 1][r] = f2b(v.y);
    Bs[4 * cq + 2][r] = f2b(v.z);
    Bs[4 * cq + 3][r] = f2b(v.w);
  }
  __syncthreads();
  facc acc[2][8];
  #pragma unroll
  for (int i = 0; i < 2; ++i)
    #pragma unroll
    for (int j = 0; j < 8; ++j)
      acc[i][j] = (facc)(0.f);
  #pragma unroll
  for (int ks = 0; ks < 2; ++ks) {
    bfrag af0 = ld_frag(&As[wave * 32 + nl][ks * 32 + g * 8]);
    bfrag af1 = ld_frag(&As[wave * 32 + 16 + nl][ks * 32 + g * 8]);
    #pragma unroll
    for (int nt = 0; nt < 8; ++nt) {
      bfrag bfr = ld_frag(&Bs[nt * 16 + nl][ks * 32 + g * 8]);
      acc[0][nt] = __builtin_amdgcn_mfma_f32_16x16x32_bf16(af0, bfr, acc[0][nt], 0, 0, 0);
      acc[1][nt] = __builtin_amdgcn_mfma_f32_16x16x32_bf16(af1, bfr, acc[1][nt], 0, 0, 0);
    }
  }
  #pragma unroll
  for (int mt = 0; mt < 2; ++mt) {
    int mrow = m0 + wave * 32 + mt * 16 + 4 * g;
    #pragma unroll
    for (int nt = 0; nt < 8; ++nt) {
      facc a = acc[mt][nt];
      int c = n0 + nt * 16 + nl;
      #pragma unroll
      for (int r = 0; r < 4; ++r)
        out[(size_t)(mrow + r) * DM + c] = a[r];
    }
  }
}

extern "C" void kernel_launch(void* const* d_in, const int* in_sizes, int n_in,
                              void* d_out, int out_size, void* d_ws, size_t ws_size,
                              hipStream_t stream) {
  const float* x      = (const float*)d_in[0];
  const float* Win    = (const float*)d_in[1];
  const float* conv_w = (const float*)d_in[2];
  const float* conv_b = (const float*)d_in[3];
  const float* Wx     = (const float*)d_in[4];
  const float* Wdt    = (const float*)d_in[5];
  const float* bdt    = (const float*)d_in[6];
  const float* A_log  = (const float*)d_in[7];
  const float* Dp     = (const float*)d_in[8];
  const float* Wout   = (const float*)d_in[9];
  float* out = (float*)d_out;

  float* ws = (float*)d_ws;
  const size_t SZ = (size_t)BL * 64;              // 1M floats
  const size_t CH = (size_t)B_ * E_ * NCH * 64;   // 512K floats
  float* xp_pre = ws + 0 * SZ;
  float* resT   = ws + 1 * SZ;
  float* xpT    = ws + 2 * SZ;
  float* deltaT = ws + 3 * SZ;
  u32*   BCm    = (u32*)(ws + 4 * SZ);            // packed B|C<<16, SZ u32s
  float* ygT    = ws + 5 * SZ;
  float* Ssum   = ws + 6 * SZ;
  float* Pp     = ws + 6 * SZ + 1 * CH;
  unsigned short* WFT = (unsigned short*)(ws + 6 * SZ + 2 * CH);
  // WinTk (bf16 copy of Win, 128KB) lives at the head of the ygT region:
  // written by k_wfuse, read only by k_gemm_in, fully overwritten by k_scan3
  // before k_gemm_out reads ygT. Total ws footprint unchanged.
  unsigned short* WinTk = (unsigned short*)(ws + 5 * SZ);

  hipLaunchKernelGGL(k_wfuse,    dim3(256),               dim3(64),  0, stream,
                     Wx, Wdt, Win, WFT, WinTk);
  hipLaunchKernelGGL(k_gemm_in,  dim3(BL / 32),           dim3(256), 0, stream,
                     x, WinTk, xp_pre, resT);
  hipLaunchKernelGGL(k_fused,    dim3(BL / 32),           dim3(256), 0, stream,
                     xp_pre, conv_w, conv_b, WFT, bdt, xpT, deltaT, BCm);
  hipLaunchKernelGGL(k_scan1,    dim3(B_ * E_ * NCH / 4), dim3(256), 0, stream,
                     deltaT, xpT, BCm, A_log, Ssum, Pp);
  hipLaunchKernelGGL(k_scan3,    dim3(B_ * E_ * NCH / 4), dim3(256), 0, stream,
                     deltaT, xpT, resT, BCm, A_log, Dp, Ssum, Pp, ygT);
  hipLaunchKernelGGL(k_gemm_out, dim3(1024),              dim3(128), 0, stream, ygT, Wout, out);
}

// Round 6
// 167.967 us; speedup vs baseline: 1.2710x; 1.0146x over previous
//
#include <hip/hip_runtime.h>
#include <hip/hip_bf16.h>

#define B_ 8
#define L_ 2048
#define DM 512
#define E_ 64
#define H_ 64
#define R_ 4
#define KC 3
#define BL (B_*L_)   // 16384
#define NX 132       // R + 2H
#define LC 128       // scan chunk length
#define NCH (L_/LC)  // 16 chunks

typedef __attribute__((ext_vector_type(8))) short bfrag;
typedef __attribute__((ext_vector_type(4))) float facc;
typedef unsigned int u32;

#define LOG2E 1.4426950408889634f

__device__ __forceinline__ unsigned short f2b(float f) {
  __hip_bfloat16 h = __float2bfloat16(f);
  return *reinterpret_cast<unsigned short*>(&h);
}
__device__ __forceinline__ float b2f16(unsigned short u) {
  return __uint_as_float((unsigned)u << 16);
}
__device__ __forceinline__ bfrag ld_frag(const unsigned short* p) {
  bfrag t;
  __builtin_memcpy(&t, p, 16);
  return t;
}

// ---- K0: blocks 0..191: fold W_dt into W_x -> WFT bf16 [192][64] (n-major).
// blocks 192..255: Win f32 -> WinTk bf16 (same [512][128] layout).
// blocks 256..319: Wout f32 [64][512] -> WoutT bf16 [512][64] (n-major).
__global__ __launch_bounds__(64) void k_wfuse(
    const float* __restrict__ Wx, const float* __restrict__ Wdt,
    const float* __restrict__ Win, const float* __restrict__ Wout,
    unsigned short* __restrict__ WFT, unsigned short* __restrict__ WinTk,
    unsigned short* __restrict__ WoutT)
{
  if (blockIdx.x >= 256) {
    const int gid = (blockIdx.x - 256) * 64 + threadIdx.x;   // 0..4095
    #pragma unroll
    for (int i = gid; i < E_ * DM; i += 4096) {
      int e = i >> 9, n = i & 511;       // read Wout[i] coalesced
      WoutT[n * 64 + e] = f2b(Wout[i]);
    }
    return;
  }
  if (blockIdx.x >= 192) {
    const int gid = (blockIdx.x - 192) * 64 + threadIdx.x;   // 0..4095
    const float4* src = (const float4*)Win;
    #pragma unroll
    for (int i = gid; i < DM * 128 / 4; i += 4096) {
      float4 v = src[i];
      ushort4 u;
      u.x = f2b(v.x); u.y = f2b(v.y); u.z = f2b(v.z); u.w = f2b(v.w);
      *(ushort4*)&WinTk[i * 4] = u;
    }
    return;
  }
  const int n = blockIdx.x;
  const int e = threadIdx.x;
  float v;
  if (n < 64) {
    v = 0.f;
    #pragma unroll
    for (int j = 0; j < R_; ++j)
      v = fmaf(Wx[e * NX + j], Wdt[j * 64 + n], v);
  } else if (n < 128) {
    v = Wx[e * NX + R_ + (n - 64)];
  } else {
    v = Wx[e * NX + R_ + 64 + (n - 128)];
  }
  WFT[n * 64 + e] = f2b(v);
}

// ---- K1 (MFMA, M=32, BK=64, single LDS buffer, 2 barriers/iter):
// xz = x @ W_in ; cols 0..63 -> xp_pre[token][64], 64..127 -> resT
// B staged transposed from pre-converted bf16 WinTk (no in-kernel f2b for B).
__global__ __launch_bounds__(256) void k_gemm_in(
    const float* __restrict__ x, const unsigned short* __restrict__ WinTk,
    float* __restrict__ xp_pre, float* __restrict__ resT)
{
  __shared__ unsigned short As[32][72];    // 32 rows x 64 k (pad to 144B rows)
  __shared__ unsigned short Bs[128][72];   // 128 n  x 64 k
  const int tid  = threadIdx.x;
  const int m0   = blockIdx.x * 32;
  const int b    = m0 >> 11;
  const int l0   = m0 & 2047;
  const int lane = tid & 63;
  const int wave = tid >> 6;
  const int mt   = wave & 1;
  const int ng   = wave >> 1;
  const int nl   = lane & 15;
  const int g    = lane >> 4;
  // A staging: thread -> (row ar, 8 k at aq*8)
  const int ar = tid >> 3;
  const int aq = tid & 7;
  // B staging: thread -> (col n = bn, 32 k at kq*32)
  const int bn = tid & 127;
  const int kq = tid >> 7;

  facc acc[4];
  #pragma unroll
  for (int j = 0; j < 4; ++j) acc[j] = (facc)(0.f);

  for (int it = 0; it < 8; ++it) {
    const int k0 = it * 64;
    if (it) __syncthreads();
    // stage A: 32 x 64 f32 -> bf16
    #pragma unroll
    for (int p = 0; p < 2; ++p) {
      float4 v = *(const float4*)&x[(size_t)(m0 + ar) * DM + k0 + aq * 8 + 4 * p];
      ushort4 u;
      u.x = f2b(v.x); u.y = f2b(v.y); u.z = f2b(v.z); u.w = f2b(v.w);
      *(ushort4*)&As[ar][aq * 8 + 4 * p] = u;
    }
    // stage B transposed: lane reads 4 k's of column bn from bf16 WinTk
    // (2B loads, lane-consecutive n -> coalesced), packs, stores uint2
    #pragma unroll
    for (int p = 0; p < 8; ++p) {
      const unsigned short* wp = &WinTk[(size_t)(k0 + kq * 32 + 4 * p) * 128 + bn];
      u32 lo = (u32)wp[0]   | ((u32)wp[128] << 16);
      u32 hi = (u32)wp[256] | ((u32)wp[384] << 16);
      uint2 uu; uu.x = lo; uu.y = hi;
      *(uint2*)&Bs[bn][kq * 32 + 4 * p] = uu;
    }
    __syncthreads();
    #pragma unroll
    for (int ks = 0; ks < 2; ++ks) {
      bfrag af = ld_frag(&As[mt * 16 + nl][ks * 32 + g * 8]);
      #pragma unroll
      for (int nt2 = 0; nt2 < 4; ++nt2) {
        bfrag bfr = ld_frag(&Bs[(ng * 4 + nt2) * 16 + nl][ks * 32 + g * 8]);
        acc[nt2] = __builtin_amdgcn_mfma_f32_16x16x32_bf16(af, bfr, acc[nt2], 0, 0, 0);
      }
    }
  }
  #pragma unroll
  for (int nt2 = 0; nt2 < 4; ++nt2) {
    facc a = acc[nt2];
    int c = (ng * 4 + nt2) * 16 + nl;
    int mrow = mt * 16 + 4 * g;
    if (c < 64) {
      #pragma unroll
      for (int r = 0; r < 4; ++r)
        xp_pre[(size_t)(m0 + mrow + r) * 64 + c] = a[r];
    } else {
      *(float4*)&resT[(size_t)(b * 64 + (c - 64)) * L_ + l0 + mrow] =
          make_float4(a[0], a[1], a[2], a[3]);
    }
  }
}

// ---- K2 (fused, MFMA): grid 512 — each 64-token group split across 2 blocks:
// yh=0: delta tiles 0..3 (+ xpT write); yh=1: B tiles 4..7 + C tiles 8..11 (packed).
__global__ __launch_bounds__(256) void k_fused(
    const float* __restrict__ xp_pre,
    const float* __restrict__ conv_w, const float* __restrict__ conv_b,
    const unsigned short* __restrict__ WFT, const float* __restrict__ bdt,
    float* __restrict__ xpT, float* __restrict__ deltaT,
    u32* __restrict__ BCm)
{
  __shared__ float raw[66][65];
  __shared__ unsigned short rawb[64][72];     // 144B rows, 16B aligned
  __shared__ unsigned short WFb[192][72];     // staged half per block
  const int tid = threadIdx.x;
  const int grp = blockIdx.x >> 1;
  const int yh  = blockIdx.x & 1;
  const int t0 = grp * 64;
  const int b  = t0 >> 11;
  const int l0 = t0 & 2047;
  // stage raw (zero-pad l<0)
  for (int fidx = tid; fidx < 66 * 16; fidx += 256) {
    int r = fidx >> 4, cg = fidx & 15;
    int l = l0 - 2 + r;
    float4 v = make_float4(0.f, 0.f, 0.f, 0.f);
    if (l >= 0) v = *(const float4*)&xp_pre[((size_t)b * L_ + l) * 64 + cg * 4];
    raw[r][cg * 4 + 0] = v.x;
    raw[r][cg * 4 + 1] = v.y;
    raw[r][cg * 4 + 2] = v.z;
    raw[r][cg * 4 + 3] = v.w;
  }
  // stage the WFb rows this block needs: yh=0 -> rows 0..63; yh=1 -> rows 64..191
  {
    const int nbase = yh ? 64 : 0;
    const int nrows = yh ? 128 : 64;
    for (int i4 = tid; i4 < nrows * 16; i4 += 256) {
      int n = nbase + (i4 >> 4), jq = i4 & 15;
      *(ushort4*)&WFb[n][jq * 4] = *(const ushort4*)&WFT[n * 64 + jq * 4];
    }
  }
  __syncthreads();
  // conv + silu: thread -> (e, 16 tokens); write bf16 A-tile (+ xpT if yh==0)
  const int e  = tid & 63;
  const int tl = tid >> 6;
  const float w0 = conv_w[e * KC + 0], w1 = conv_w[e * KC + 1], w2 = conv_w[e * KC + 2];
  const float cb = conv_b[e];
  float cres[16];
  #pragma unroll
  for (int i = 0; i < 16; ++i) {
    int tok = tl * 16 + i;
    float a = cb;
    a = fmaf(raw[tok + 0][e], w0, a);
    a = fmaf(raw[tok + 1][e], w1, a);
    a = fmaf(raw[tok + 2][e], w2, a);
    cres[i] = a / (1.f + __expf(-a));
  }
  #pragma unroll
  for (int i = 0; i < 16; ++i) rawb[tl * 16 + i][e] = f2b(cres[i]);
  if (yh == 0) {
    #pragma unroll
    for (int i = 0; i < 16; i += 4)
      *(float4*)&xpT[(size_t)(b * 64 + e) * L_ + l0 + tl * 16 + i] =
          make_float4(cres[i], cres[i + 1], cres[i + 2], cres[i + 3]);
  }
  __syncthreads();
  // MFMA GEMM: M=64 (4 waves x 16 rows), K=64 (2 ksteps); N-tiles split by yh.
  const int wave = tid >> 6;
  const int lane = tid & 63;
  const int nl   = lane & 15;
  const int g    = lane >> 4;
  const int mrow = wave * 16 + 4 * g;
  if (yh == 0) {
    facc acc[4];
    #pragma unroll
    for (int j = 0; j < 4; ++j) acc[j] = (facc)(0.f);
    #pragma unroll
    for (int ks = 0; ks < 2; ++ks) {
      bfrag af = ld_frag(&rawb[wave * 16 + nl][ks * 32 + g * 8]);
      #pragma unroll
      for (int nt = 0; nt < 4; ++nt) {
        bfrag bfr = ld_frag(&WFb[nt * 16 + nl][ks * 32 + g * 8]);
        acc[nt] = __builtin_amdgcn_mfma_f32_16x16x32_bf16(af, bfr, acc[nt], 0, 0, 0);
      }
    }
    // delta cols (0..63): softplus -> deltaT (transposed, coalesced)
    #pragma unroll
    for (int nt = 0; nt < 4; ++nt) {
      facc a = acc[nt];
      int c = nt * 16 + nl;
      float bias = bdt[c];
      float d0 = a[0] + bias, d1 = a[1] + bias, d2 = a[2] + bias, d3 = a[3] + bias;
      float4 dv;
      dv.x = (d0 > 20.f) ? d0 : log1pf(__expf(d0));
      dv.y = (d1 > 20.f) ? d1 : log1pf(__expf(d1));
      dv.z = (d2 > 20.f) ? d2 : log1pf(__expf(d2));
      dv.w = (d3 > 20.f) ? d3 : log1pf(__expf(d3));
      *(float4*)&deltaT[(size_t)(b * 64 + c) * L_ + l0 + mrow] = dv;
    }
  } else {
    facc acc[8];
    #pragma unroll
    for (int j = 0; j < 8; ++j) acc[j] = (facc)(0.f);
    #pragma unroll
    for (int ks = 0; ks < 2; ++ks) {
      bfrag af = ld_frag(&rawb[wave * 16 + nl][ks * 32 + g * 8]);
      #pragma unroll
      for (int j = 0; j < 8; ++j) {
        bfrag bfr = ld_frag(&WFb[(4 + j) * 16 + nl][ks * 32 + g * 8]);
        acc[j] = __builtin_amdgcn_mfma_f32_16x16x32_bf16(af, bfr, acc[j], 0, 0, 0);
      }
    }
    // B (acc 0..3, tiles 4..7) pairs with C (acc 4..7, tiles 8..11) -> pack u32
    #pragma unroll
    for (int j = 0; j < 4; ++j) {
      facc aB = acc[j];
      facc aC = acc[4 + j];
      int col = j * 16 + nl;
      #pragma unroll
      for (int r = 0; r < 4; ++r)
        BCm[(size_t)(t0 + mrow + r) * 64 + col] =
            (u32)f2b(aB[r]) | ((u32)f2b(aC[r]) << 16);
    }
  }
}

// ---- K3a: per-chunk summaries. 4 waves/block, wave-private LDS, no barriers.
__global__ __launch_bounds__(256) void k_scan1(
    const float* __restrict__ deltaT, const float* __restrict__ xpT,
    const u32* __restrict__ BCm, const float* __restrict__ A_log,
    float* __restrict__ Ssum, float* __restrict__ Pp)
{
  __shared__ float dwA[4][256];   // per wave: d[0..127], w[128..255]
  const int tid = threadIdx.x;
  const int wv  = tid >> 6;
  const int h   = tid & 63;
  const int id  = blockIdx.x * 4 + wv;
  const int c   = id & (NCH - 1);
  if (c == NCH - 1) return;       // last chunk's summary is never consumed
  const int e = (id >> 4) & 63;
  const int b = id >> 10;
  const float A2 = -__expf(A_log[e * 64 + h]) * LOG2E;   // A * log2(e)
  const size_t beL = (size_t)(b * 64 + e) * L_;
  const int l0 = c * LC;
  float* dw = dwA[wv];
  {
    float2 dv = *(const float2*)&deltaT[beL + l0 + 2 * h];
    float2 xv = *(const float2*)&xpT[beL + l0 + 2 * h];
    *(float2*)&dw[2 * h] = dv;
    *(float2*)&dw[128 + 2 * h] = make_float2(dv.x * xv.x, dv.y * xv.y);
  }
  const u32* bc = &BCm[(size_t)(b * L_ + l0) * 64 + h];
  float s = 0.f, sd = 0.f;
  #pragma unroll 2
  for (int k16 = 0; k16 < 8; ++k16) {
    #pragma unroll
    for (int kk = 0; kk < 16; ++kk) {
      const int k = k16 * 16 + kk;
      float dlt = dw[k];
      float w   = dw[128 + k];
      u32 u = bc[(size_t)k * 64];
      float Bh = __uint_as_float(u << 16);
      s = fmaf(__builtin_amdgcn_exp2f(dlt * A2), s, w * Bh);
      sd += dlt;
    }
  }
  const size_t idx = (size_t)id * 64 + h;
  Ssum[idx] = s;
  Pp[idx]   = __builtin_amdgcn_exp2f(A2 * sd);
}

// ---- K3c: scan per chunk. 4 waves/block, wave-private LDS, no barriers.
// Output y written directly as bf16 (ygTh) — same rounding point as the old
// k_gemm_out staging, so results are bit-identical.
__global__ __launch_bounds__(256) void k_scan3(
    const float* __restrict__ deltaT, const float* __restrict__ xpT,
    const float* __restrict__ resT, const u32* __restrict__ BCm,
    const float* __restrict__ A_log, const float* __restrict__ Dp,
    const float* __restrict__ Ssum, const float* __restrict__ Pp,
    unsigned short* __restrict__ ygTh)
{
  __shared__ float tileA[4][16][68];
  __shared__ float bufA[4][512];  // d[0..127] w[128..255] x[256..383] res[384..511]
  const int tid = threadIdx.x;
  const int wv  = tid >> 6;
  const int h   = tid & 63;
  const int id  = blockIdx.x * 4 + wv;
  const int c   = id & (NCH - 1);
  const int e   = (id >> 4) & 63;
  const int b   = id >> 10;
  const float A2 = -__expf(A_log[e * 64 + h]) * LOG2E;
  const float Dv = Dp[e];
  const size_t beL = (size_t)(b * 64 + e) * L_;
  float (*tile)[68] = tileA[wv];
  float* buf = bufA[wv];
  // compose entry state from chunk summaries 0..c-1 (global reads only)
  float s = 0.f;
  const size_t sbase = (size_t)(id & ~(NCH - 1)) * 64 + h;
  for (int cc = 0; cc < c; ++cc)
    s = fmaf(Pp[sbase + (size_t)cc * 64], s, Ssum[sbase + (size_t)cc * 64]);
  const int l0 = c * LC;
  {
    float2 dv = *(const float2*)&deltaT[beL + l0 + 2 * h];
    float2 xv = *(const float2*)&xpT[beL + l0 + 2 * h];
    float2 rv = *(const float2*)&resT[beL + l0 + 2 * h];
    *(float2*)&buf[2 * h]       = dv;
    *(float2*)&buf[128 + 2 * h] = make_float2(dv.x * xv.x, dv.y * xv.y);
    *(float2*)&buf[256 + 2 * h] = xv;
    *(float2*)&buf[384 + 2 * h] = rv;
  }
  const u32* bc = &BCm[(size_t)(b * L_ + l0) * 64 + h];
  const int r = h & 15, q = h >> 4;
  #pragma unroll 2
  for (int k16 = 0; k16 < 8; ++k16) {
    #pragma unroll
    for (int kk = 0; kk < 16; ++kk) {
      const int k = k16 * 16 + kk;
      float dlt = buf[k];
      float w   = buf[128 + k];
      u32 u = bc[(size_t)k * 64];
      s = fmaf(__builtin_amdgcn_exp2f(dlt * A2), s, w * __uint_as_float(u << 16));
      tile[kk][h] = s * __uint_as_float(u & 0xffff0000u);
    }
    // lane h: row r = h&15, quarter q = h>>4; sum 16 f32 then combine quarters
    float part = 0.f;
    const float4* rp = (const float4*)&tile[r][q * 16];
    #pragma unroll
    for (int jq = 0; jq < 4; ++jq) {
      float4 v = rp[jq];
      part += (v.x + v.y) + (v.z + v.w);
    }
    part += __shfl_xor(part, 16, 64);
    part += __shfl_xor(part, 32, 64);
    if (q == 0) {
      const int lk = k16 * 16 + r;
      float y = fmaf(buf[256 + lk], Dv, part);
      y *= __builtin_amdgcn_rcpf(1.f + __builtin_amdgcn_exp2f(-LOG2E * buf[384 + lk]));
      ygTh[beL + l0 + lk] = f2b(y);
    }
  }
}

// ---- K4 (MFMA): out = ygTh^T @ WoutT. Pure-copy staging (no conversions),
// single-shot + 1 barrier. 1024 blocks x 128 thr.
__global__ __launch_bounds__(128) void k_gemm_out(
    const unsigned short* __restrict__ ygTh, const unsigned short* __restrict__ WoutT,
    float* __restrict__ out)
{
  __shared__ unsigned short As[64][68];
  __shared__ unsigned short Bs[128][68];
  const int tid  = threadIdx.x;
  const int m0   = (blockIdx.x & 255) * 64;
  const int n0   = (blockIdx.x >> 8) * 128;
  const int b    = m0 >> 11;
  const int l0   = m0 & 2047;
  const int lane = tid & 63;
  const int wave = tid >> 6;
  const int nl   = lane & 15;
  const int g    = lane >> 4;
  // As[tok][e] <- ygTh[e][l0+tok]: thread reads 4 tokens of one e (ushort4)
  #pragma unroll
  for (int p = 0; p < 8; ++p) {
    int fidx = tid + 128 * p;              // 0..1023
    int e = fidx >> 4, q = fidx & 15;
    ushort4 v = *(const ushort4*)&ygTh[(size_t)(b * 64 + e) * L_ + l0 + 4 * q];
    As[4 * q + 0][e] = v.x;
    As[4 * q + 1][e] = v.y;
    As[4 * q + 2][e] = v.z;
    As[4 * q + 3][e] = v.w;
  }
  // Bs[n][e] <- WoutT[(n0+n)*64 + e]: straight ushort4 copies
  #pragma unroll
  for (int p = 0; p < 16; ++p) {
    int fidx = tid + 128 * p;              // 0..2047
    int n = fidx >> 4, jq = fidx & 15;
    *(ushort4*)&Bs[n][4 * jq] = *(const ushort4*)&WoutT[(size_t)(n0 + n) * 64 + 4 * jq];
  }
  __syncthreads();
  facc acc[2][8];
  #pragma unroll
  for (int i = 0; i < 2; ++i)
    #pragma unroll
    for (int j = 0; j < 8; ++j)
      acc[i][j] = (facc)(0.f);
  #pragma unroll
  for (int ks = 0; ks < 2; ++ks) {
    bfrag af0 = ld_frag(&As[wave * 32 + nl][ks * 32 + g * 8]);
    bfrag af1 = ld_frag(&As[wave * 32 + 16 + nl][ks * 32 + g * 8]);
    #pragma unroll
    for (int nt = 0; nt < 8; ++nt) {
      bfrag bfr = ld_frag(&Bs[nt * 16 + nl][ks * 32 + g * 8]);
      acc[0][nt] = __builtin_amdgcn_mfma_f32_16x16x32_bf16(af0, bfr, acc[0][nt], 0, 0, 0);
      acc[1][nt] = __builtin_amdgcn_mfma_f32_16x16x32_bf16(af1, bfr, acc[1][nt], 0, 0, 0);
    }
  }
  #pragma unroll
  for (int mt = 0; mt < 2; ++mt) {
    int mrow = m0 + wave * 32 + mt * 16 + 4 * g;
    #pragma unroll
    for (int nt = 0; nt < 8; ++nt) {
      facc a = acc[mt][nt];
      int c = n0 + nt * 16 + nl;
      #pragma unroll
      for (int r = 0; r < 4; ++r)
        out[(size_t)(mrow + r) * DM + c] = a[r];
    }
  }
}

extern "C" void kernel_launch(void* const* d_in, const int* in_sizes, int n_in,
                              void* d_out, int out_size, void* d_ws, size_t ws_size,
                              hipStream_t stream) {
  const float* x      = (const float*)d_in[0];
  const float* Win    = (const float*)d_in[1];
  const float* conv_w = (const float*)d_in[2];
  const float* conv_b = (const float*)d_in[3];
  const float* Wx     = (const float*)d_in[4];
  const float* Wdt    = (const float*)d_in[5];
  const float* bdt    = (const float*)d_in[6];
  const float* A_log  = (const float*)d_in[7];
  const float* Dp     = (const float*)d_in[8];
  const float* Wout   = (const float*)d_in[9];
  float* out = (float*)d_out;

  float* ws = (float*)d_ws;
  const size_t SZ = (size_t)BL * 64;              // 1M floats
  const size_t CH = (size_t)B_ * E_ * NCH * 64;   // 512K floats
  float* xp_pre = ws + 0 * SZ;
  float* resT   = ws + 1 * SZ;
  float* xpT    = ws + 2 * SZ;
  float* deltaT = ws + 3 * SZ;
  u32*   BCm    = (u32*)(ws + 4 * SZ);            // packed B|C<<16, SZ u32s
  float* Ssum   = ws + 6 * SZ;
  float* Pp     = ws + 6 * SZ + 1 * CH;
  unsigned short* WFT = (unsigned short*)(ws + 6 * SZ + 2 * CH);
  // Region ws+5*SZ (4MB), time-shared — footprint unchanged:
  //   [0 .. 2MB)        ygTh bf16 (written by scan3, read by gemm_out)
  //   [2MB .. 2MB+128K) WinTk bf16 (wfuse -> gemm_in; dead before scan3 runs)
  //   [2MB+128K .. +64K) WoutT bf16 (wfuse -> gemm_out; never overwritten)
  unsigned short* base5 = (unsigned short*)(ws + 5 * SZ);
  unsigned short* ygTh  = base5;
  unsigned short* WinTk = base5 + (1u << 20);
  unsigned short* WoutT = WinTk + DM * 128;

  hipLaunchKernelGGL(k_wfuse,    dim3(320),               dim3(64),  0, stream,
                     Wx, Wdt, Win, Wout, WFT, WinTk, WoutT);
  hipLaunchKernelGGL(k_gemm_in,  dim3(BL / 32),           dim3(256), 0, stream,
                     x, WinTk, xp_pre, resT);
  hipLaunchKernelGGL(k_fused,    dim3(BL / 32),           dim3(256), 0, stream,
                     xp_pre, conv_w, conv_b, WFT, bdt, xpT, deltaT, BCm);
  hipLaunchKernelGGL(k_scan1,    dim3(B_ * E_ * NCH / 4), dim3(256), 0, stream,
                     deltaT, xpT, BCm, A_log, Ssum, Pp);
  hipLaunchKernelGGL(k_scan3,    dim3(B_ * E_ * NCH / 4), dim3(256), 0, stream,
                     deltaT, xpT, resT, BCm, A_log, Dp, Ssum, Pp, ygTh);
  hipLaunchKernelGGL(k_gemm_out, dim3(1024),              dim3(128), 0, stream,
                     ygTh, WoutT, out);
}